// Round 2
// baseline (861.023 us; speedup 1.0000x reference)
//
#include <hip/hip_runtime.h>

#define NN 32      // nodes
#define FF 64      // GAT out features
#define HH 128     // LSTM hidden
#define G4 512     // 4*H
#define BB 32      // batch
#define TT 512     // time steps
#define ET 128     // 96 edges + 32 self loops
#define NPOS (BB*TT)

__device__ __forceinline__ float frcp(float x) { return __builtin_amdgcn_rcpf(x); }
__device__ __forceinline__ float sigm(float x) { return frcp(1.f + __expf(-x)); }
__device__ __forceinline__ float tanh_fast(float x) { return 1.f - 2.f * frcp(1.f + __expf(2.f * x)); }

// ---------------- prep: fold GAT linear into LSTM input weights ----------------
// W_eff[n,j]  = sum_f w_gat[f] * W_ih[n*FF+f, j]
// biasp[n,j]  = sum_f b_gat[f] * W_ih[n*FF+f, j]   (partial; reduced in prep2)
__global__ __launch_bounds__(512) void prep_kernel(const float* __restrict__ w_gat,
                                                   const float* __restrict__ b_gat,
                                                   const float* __restrict__ W_ih,
                                                   float* __restrict__ W_eff,
                                                   float* __restrict__ biasp) {
  int j = threadIdx.x;
  int n = blockIdx.x;
  float accw = 0.f, accb = 0.f;
#pragma unroll 8
  for (int f = 0; f < FF; ++f) {
    float wv = W_ih[(n * FF + f) * G4 + j];
    accw = fmaf(w_gat[f], wv, accw);
    accb = fmaf(b_gat[f], wv, accb);
  }
  W_eff[n * G4 + j] = accw;
  biasp[n * G4 + j] = accb;
}

// bias_eff[j] = b_ih[j] + b_hh[j] + sum_n biasp[n,j];  scal = {w.att_src, w.att_dst}
__global__ __launch_bounds__(512) void prep2_kernel(const float* __restrict__ biasp,
                                                    const float* __restrict__ b_ih,
                                                    const float* __restrict__ b_hh,
                                                    const float* __restrict__ w_gat,
                                                    const float* __restrict__ att_src,
                                                    const float* __restrict__ att_dst,
                                                    float* __restrict__ bias_eff,
                                                    float* __restrict__ scal) {
  int j = threadIdx.x;
  float acc = b_ih[j] + b_hh[j];
#pragma unroll
  for (int n = 0; n < NN; ++n) acc += biasp[n * G4 + j];
  bias_eff[j] = acc;
  if (j == 0) {
    float cs = 0.f, cd = 0.f;
    for (int f = 0; f < FF; ++f) {
      cs = fmaf(w_gat[f], att_src[f], cs);
      cd = fmaf(w_gat[f], att_dst[f], cd);
    }
    scal[0] = cs;
    scal[1] = cd;
  }
}

// ---------------- GAT attention scalars: s[pos,n] ----------------
// block = 256 threads = 8 positions x 32 nodes
__global__ __launch_bounds__(256) void gat_kernel(const float* __restrict__ x_seq,
                                                  const int* __restrict__ ei,
                                                  const float* __restrict__ scal,
                                                  float* __restrict__ s_buf) {
  __shared__ int ep[ET];
  __shared__ float xs[8 * 33];  // +1 pad per row
  int tid = threadIdx.x;
  if (tid < ET) {
    int s, d;
    if (tid < 96) { s = ei[tid]; d = ei[96 + tid]; }
    else { s = tid - 96; d = tid - 96; }
    ep[tid] = s | (d << 16);
  }
  int p = tid >> 5, n = tid & 31;
  int pos = blockIdx.x * 8 + p;
  xs[p * 33 + n] = x_seq[pos * NN + n];  // coalesced: blockIdx*256 + tid
  __syncthreads();
  float cs = scal[0], cd = scal[1];
  int base = p * 33;
  // pass 1: segment max over edges with dst == n
  float m = -3.0e38f;
  for (int e = 0; e < ET; ++e) {
    int pe = ep[e];
    int se = pe & 0xffff, de = pe >> 16;
    float ev = cs * xs[base + se] + cd * xs[base + de];
    ev = ev > 0.f ? ev : 0.2f * ev;  // LeakyReLU(0.2)
    if (de == n) m = fmaxf(m, ev);
  }
  // pass 2: softmax-weighted sum of x[src]
  float z = 0.f, sa = 0.f;
  for (int e = 0; e < ET; ++e) {
    int pe = ep[e];
    int se = pe & 0xffff, de = pe >> 16;
    float xsv = xs[base + se];
    float ev = cs * xsv + cd * xs[base + de];
    ev = ev > 0.f ? ev : 0.2f * ev;
    float ex = __expf(ev - m);
    float exm = (de == n) ? ex : 0.f;
    z += exm;
    sa = fmaf(exm, xsv, sa);
  }
  s_buf[pos * NN + n] = sa * frcp(z);
}

// ---------------- xw[pos,j] = s[pos,:] @ W_eff[:,j] + bias_eff[j] ----------------
__global__ __launch_bounds__(256) void xw_kernel(const float* __restrict__ s_buf,
                                                 const float* __restrict__ W_eff,
                                                 const float* __restrict__ bias_eff,
                                                 float* __restrict__ xw) {
  __shared__ float sl[32 * NN];
  int tid = threadIdx.x;
  int posbase = blockIdx.x * 32;
#pragma unroll
  for (int r = 0; r < 4; ++r) sl[tid + r * 256] = s_buf[posbase * NN + tid + r * 256];
  float we0[NN], we1[NN];
#pragma unroll
  for (int nn = 0; nn < NN; ++nn) {
    we0[nn] = W_eff[nn * G4 + tid];
    we1[nn] = W_eff[nn * G4 + 256 + tid];
  }
  float b0 = bias_eff[tid], b1 = bias_eff[256 + tid];
  __syncthreads();
  for (int p = 0; p < 32; ++p) {
    const float4* sp = (const float4*)&sl[p * NN];
    float a0 = b0, a1 = b1;
#pragma unroll
    for (int q = 0; q < 8; ++q) {
      float4 sv = sp[q];
      a0 = fmaf(sv.x, we0[4 * q], a0);
      a0 = fmaf(sv.y, we0[4 * q + 1], a0);
      a0 = fmaf(sv.z, we0[4 * q + 2], a0);
      a0 = fmaf(sv.w, we0[4 * q + 3], a0);
      a1 = fmaf(sv.x, we1[4 * q], a1);
      a1 = fmaf(sv.y, we1[4 * q + 1], a1);
      a1 = fmaf(sv.z, we1[4 * q + 2], a1);
      a1 = fmaf(sv.w, we1[4 * q + 3], a1);
    }
    xw[(posbase + p) * G4 + tid] = a0;
    xw[(posbase + p) * G4 + 256 + tid] = a1;
  }
}

// ---------------- LSTM scan ----------------
// One block (1024 thr, 16 waves) per batch. Lane pair (2m, 2m+1) owns gate
// j = tid>>1: each holds 64 of W_hh's column j in VGPRs (pinned via asm) and
// does half the h-dot; pair-reduce via same-wave shfl_xor(1). Threads <128
// own cell state c and the h update.
__global__ __launch_bounds__(1024, 4) void lstm_kernel(const float* __restrict__ xw,
                                                       const float* __restrict__ W_hh,
                                                       const float* __restrict__ W_fc,
                                                       const float* __restrict__ b_fc,
                                                       float* __restrict__ out) {
  __shared__ float h_sh[HH];
  __shared__ float act[G4];
  int b = blockIdx.x, tid = threadIdx.x;
  int j = tid >> 1, half = tid & 1;
  float w[HH / 2];  // 64 weights of column j, rows [half*64, half*64+64)
#pragma unroll
  for (int k = 0; k < HH / 2; ++k) w[k] = W_hh[(half * (HH / 2) + k) * G4 + j];
#pragma unroll
  for (int k = 0; k < HH / 2; ++k) asm volatile("" : "+v"(w[k]));  // pin in VGPRs, forbid remat
  float c = 0.f;  // cell state, valid for tid < HH
  if (tid < HH) h_sh[tid] = 0.f;
  bool is_g = (j >> 7) == 2;  // gate order i,f,g,o
  const float* xwb = xw + (size_t)b * TT * G4;
  const float4* hp = (const float4*)h_sh + half * (HH / 8);  // this half's 64 h values
  __syncthreads();
  for (int t = 0; t < TT; ++t) {
    float xv = xwb[t * G4 + j];  // issued early, consumed after the dot
    float acc0 = 0.f, acc1 = 0.f;
#pragma unroll
    for (int q = 0; q < HH / 8; q += 2) {
      float4 h0 = hp[q];
      float4 h1 = hp[q + 1];
      acc0 = fmaf(h0.x, w[4 * q], acc0);
      acc0 = fmaf(h0.y, w[4 * q + 1], acc0);
      acc0 = fmaf(h0.z, w[4 * q + 2], acc0);
      acc0 = fmaf(h0.w, w[4 * q + 3], acc0);
      acc1 = fmaf(h1.x, w[4 * q + 4], acc1);
      acc1 = fmaf(h1.y, w[4 * q + 5], acc1);
      acc1 = fmaf(h1.z, w[4 * q + 6], acc1);
      acc1 = fmaf(h1.w, w[4 * q + 7], acc1);
    }
    float sum = acc0 + acc1;
    sum += __shfl_xor(sum, 1, 64);  // pair-reduce within wave
    float acc = sum + xv;
    if (!half) {
      float a = is_g ? tanh_fast(acc) : sigm(acc);
      act[j] = a;
    }
    __syncthreads();  // act visible + all h_sh reads done
    if (tid < HH) {
      float ig = act[tid], fg = act[HH + tid], gg = act[2 * HH + tid], og = act[3 * HH + tid];
      c = fmaf(fg, c, ig * gg);
      h_sh[tid] = og * tanh_fast(c);
    }
    __syncthreads();  // h_sh ready for next step
  }
  // classifier: out[b, cls] = h_T . W_fc[:, cls] + b_fc[cls]
  if (tid < 4) {
    float acc = b_fc[tid];
#pragma unroll 8
    for (int k = 0; k < HH; ++k) acc = fmaf(h_sh[k], W_fc[k * 4 + tid], acc);
    out[b * 4 + tid] = acc;
  }
}

extern "C" void kernel_launch(void* const* d_in, const int* in_sizes, int n_in,
                              void* d_out, int out_size, void* d_ws, size_t ws_size,
                              hipStream_t stream) {
  const float* x_seq   = (const float*)d_in[0];
  const int*   ei      = (const int*)d_in[1];
  const float* w_gat   = (const float*)d_in[2];
  const float* att_src = (const float*)d_in[3];
  const float* att_dst = (const float*)d_in[4];
  const float* b_gat   = (const float*)d_in[5];
  const float* W_ih    = (const float*)d_in[6];
  const float* W_hh    = (const float*)d_in[7];
  const float* b_ih    = (const float*)d_in[8];
  const float* b_hh    = (const float*)d_in[9];
  const float* W_fc    = (const float*)d_in[10];
  const float* b_fc    = (const float*)d_in[11];

  float* ws = (float*)d_ws;
  float* s_buf    = ws;                          // 16384*32   = 524288 f
  float* xw       = s_buf + (size_t)NPOS * NN;   // 16384*512  = 8388608 f
  float* W_eff    = xw + (size_t)NPOS * G4;      // 32*512     = 16384 f
  float* bias_eff = W_eff + NN * G4;             // 512 f
  float* scal     = bias_eff + G4;               // 2 f
  float* biasp    = s_buf;                       // alias: consumed by prep2 before gat overwrites

  prep_kernel<<<NN, G4, 0, stream>>>(w_gat, b_gat, W_ih, W_eff, biasp);
  prep2_kernel<<<1, G4, 0, stream>>>(biasp, b_ih, b_hh, w_gat, att_src, att_dst, bias_eff, scal);
  gat_kernel<<<NPOS / 8, 256, 0, stream>>>(x_seq, ei, scal, s_buf);
  xw_kernel<<<NPOS / 32, 256, 0, stream>>>(s_buf, W_eff, bias_eff, xw);
  lstm_kernel<<<BB, 1024, 0, stream>>>(xw, W_hh, W_fc, b_fc, (float*)d_out);
}

// Round 3
// 592.484 us; speedup vs baseline: 1.4532x; 1.4532x over previous
//
#include <hip/hip_runtime.h>

#define NN 32      // nodes
#define FF 64      // GAT out features
#define HH 128     // LSTM hidden
#define G4 512     // 4*H
#define BB 32      // batch
#define TT 512     // time steps
#define ET 128     // 96 edges + 32 self loops
#define NPOS (BB*TT)

__device__ __forceinline__ float frcp(float x) { return __builtin_amdgcn_rcpf(x); }
__device__ __forceinline__ float sigm(float x) { return frcp(1.f + __expf(-x)); }
__device__ __forceinline__ float tanh_fast(float x) { return 1.f - 2.f * frcp(1.f + __expf(2.f * x)); }

// raw barrier: LDS drain only — does NOT drain vmcnt, so global prefetches
// issued before it stay in flight (unlike __syncthreads, which drains vmcnt(0))
#define LDS_BARRIER() asm volatile("s_waitcnt lgkmcnt(0)\n\ts_barrier" ::: "memory")

// ---------------- prep: fold GAT linear into LSTM input weights ----------------
// W_eff[n,j]  = sum_f w_gat[f] * W_ih[n*FF+f, j]
// biasp[n,j]  = sum_f b_gat[f] * W_ih[n*FF+f, j]   (partial; reduced in prep2)
__global__ __launch_bounds__(512) void prep_kernel(const float* __restrict__ w_gat,
                                                   const float* __restrict__ b_gat,
                                                   const float* __restrict__ W_ih,
                                                   float* __restrict__ W_eff,
                                                   float* __restrict__ biasp) {
  int j = threadIdx.x;
  int n = blockIdx.x;
  float accw = 0.f, accb = 0.f;
#pragma unroll 8
  for (int f = 0; f < FF; ++f) {
    float wv = W_ih[(n * FF + f) * G4 + j];
    accw = fmaf(w_gat[f], wv, accw);
    accb = fmaf(b_gat[f], wv, accb);
  }
  W_eff[n * G4 + j] = accw;
  biasp[n * G4 + j] = accb;
}

// bias_eff[j] = b_ih[j] + b_hh[j] + sum_n biasp[n,j];  scal = {w.att_src, w.att_dst}
__global__ __launch_bounds__(512) void prep2_kernel(const float* __restrict__ biasp,
                                                    const float* __restrict__ b_ih,
                                                    const float* __restrict__ b_hh,
                                                    const float* __restrict__ w_gat,
                                                    const float* __restrict__ att_src,
                                                    const float* __restrict__ att_dst,
                                                    float* __restrict__ bias_eff,
                                                    float* __restrict__ scal) {
  int j = threadIdx.x;
  float acc = b_ih[j] + b_hh[j];
#pragma unroll
  for (int n = 0; n < NN; ++n) acc += biasp[n * G4 + j];
  bias_eff[j] = acc;
  if (j == 0) {
    float cs = 0.f, cd = 0.f;
    for (int f = 0; f < FF; ++f) {
      cs = fmaf(w_gat[f], att_src[f], cs);
      cd = fmaf(w_gat[f], att_dst[f], cd);
    }
    scal[0] = cs;
    scal[1] = cd;
  }
}

// ---------------- fused GAT + xw: 8 positions per 256-thread block ----------------
// stage 1: s[p,n] = softmax-weighted neighbor sum (s kept in LDS)
// stage 2: xw[pos,j] = s[pos,:] @ W_eff[:,j] + bias_eff[j]
__global__ __launch_bounds__(256) void gatxw_kernel(const float* __restrict__ x_seq,
                                                    const int* __restrict__ ei,
                                                    const float* __restrict__ scal,
                                                    const float* __restrict__ W_eff,
                                                    const float* __restrict__ bias_eff,
                                                    float* __restrict__ xw) {
  __shared__ int ep[ET];
  __shared__ float xs[8 * 32];
  __shared__ float sl[8 * 32];
  int tid = threadIdx.x;
  int posbase = blockIdx.x * 8;
  // W_eff columns for stage 2 (issued early; latency hidden behind stage 1)
  float we0[NN], we1[NN];
#pragma unroll
  for (int nn = 0; nn < NN; ++nn) {
    we0[nn] = W_eff[nn * G4 + tid];
    we1[nn] = W_eff[nn * G4 + 256 + tid];
  }
  float b0 = bias_eff[tid], b1 = bias_eff[256 + tid];
  if (tid < ET) {
    int s, d;
    if (tid < 96) { s = ei[tid]; d = ei[96 + tid]; }
    else { s = tid - 96; d = tid - 96; }
    ep[tid] = s | (d << 16);
  }
  int p = tid >> 5, n = tid & 31;
  xs[tid] = x_seq[posbase * NN + tid];  // coalesced
  __syncthreads();
  float cs = scal[0], cd = scal[1];
  int base = p * 32;
  // pass 1: segment max over edges with dst == n (2-addr LDS broadcast: free)
  float m = -3.0e38f;
  for (int e = 0; e < ET; ++e) {
    int pe = ep[e];
    int se = pe & 0xffff, de = pe >> 16;
    float ev = cs * xs[base + se] + cd * xs[base + de];
    ev = ev > 0.f ? ev : 0.2f * ev;  // LeakyReLU(0.2)
    if (de == n) m = fmaxf(m, ev);
  }
  // pass 2: softmax-weighted sum of x[src]
  float z = 0.f, sa = 0.f;
  for (int e = 0; e < ET; ++e) {
    int pe = ep[e];
    int se = pe & 0xffff, de = pe >> 16;
    float xsv = xs[base + se];
    float ev = cs * xsv + cd * xs[base + de];
    ev = ev > 0.f ? ev : 0.2f * ev;
    float ex = __expf(ev - m);
    float exm = (de == n) ? ex : 0.f;
    z += exm;
    sa = fmaf(exm, xsv, sa);
  }
  sl[p * 32 + n] = sa * frcp(z);
  __syncthreads();
  // stage 2: 8 positions x 2 columns per thread
  for (int pp = 0; pp < 8; ++pp) {
    const float4* sp = (const float4*)&sl[pp * 32];
    float a0 = b0, a1 = b1;
#pragma unroll
    for (int q = 0; q < 8; ++q) {
      float4 sv = sp[q];
      a0 = fmaf(sv.x, we0[4 * q], a0);
      a0 = fmaf(sv.y, we0[4 * q + 1], a0);
      a0 = fmaf(sv.z, we0[4 * q + 2], a0);
      a0 = fmaf(sv.w, we0[4 * q + 3], a0);
      a1 = fmaf(sv.x, we1[4 * q], a1);
      a1 = fmaf(sv.y, we1[4 * q + 1], a1);
      a1 = fmaf(sv.z, we1[4 * q + 2], a1);
      a1 = fmaf(sv.w, we1[4 * q + 3], a1);
    }
    size_t row = (size_t)(posbase + pp) * G4;
    xw[row + tid] = a0;
    xw[row + 256 + tid] = a1;
  }
}

// ---------------- LSTM scan: one block per batch, thread j owns gate column j ----------------
// Weights loaded via volatile pointer: volatile loads cannot be rematerialized
// or duplicated, forcing the 128 floats to stay register-resident across the
// t-loop (R1: compiler re-loaded them every step -> VMEM-issue bound;
// R2: asm pin at 128-reg cap -> AGPR spill + accvgpr_read per FMA).
__global__ __launch_bounds__(512, 2) void lstm_kernel(const float* __restrict__ xw,
                                                      const float* __restrict__ W_hh,
                                                      const float* __restrict__ W_fc,
                                                      const float* __restrict__ b_fc,
                                                      float* __restrict__ out) {
  __shared__ float h_sh[HH];
  __shared__ float act[G4];
  int b = blockIdx.x, j = threadIdx.x;
  const volatile float* wvp = W_hh + j;
  float w[HH];
#pragma unroll
  for (int k = 0; k < HH; ++k) w[k] = wvp[k * G4];
  float c = 0.f;  // cell state, valid for j < HH
  if (j < HH) h_sh[j] = 0.f;
  bool is_g = (j >> 7) == 2;  // gate order i,f,g,o
  const float* xp = xw + (size_t)b * TT * G4 + j;
  __syncthreads();
  float xv = *xp;  // x for t=0
  const float4* hp = (const float4*)h_sh;
#pragma unroll 1
  for (int t = 0; t < TT; ++t) {
    xp += G4;
    float xn = *xp;  // prefetch x for t+1; stays in flight across raw barriers
    float acc0 = 0.f, acc1 = 0.f, acc2 = 0.f, acc3 = 0.f;
#pragma unroll
    for (int q = 0; q < HH / 4; q += 4) {
      float4 h0 = hp[q], h1 = hp[q + 1], h2 = hp[q + 2], h3 = hp[q + 3];
      acc0 = fmaf(h0.x, w[4 * q + 0], acc0);
      acc0 = fmaf(h0.y, w[4 * q + 1], acc0);
      acc0 = fmaf(h0.z, w[4 * q + 2], acc0);
      acc0 = fmaf(h0.w, w[4 * q + 3], acc0);
      acc1 = fmaf(h1.x, w[4 * q + 4], acc1);
      acc1 = fmaf(h1.y, w[4 * q + 5], acc1);
      acc1 = fmaf(h1.z, w[4 * q + 6], acc1);
      acc1 = fmaf(h1.w, w[4 * q + 7], acc1);
      acc2 = fmaf(h2.x, w[4 * q + 8], acc2);
      acc2 = fmaf(h2.y, w[4 * q + 9], acc2);
      acc2 = fmaf(h2.z, w[4 * q + 10], acc2);
      acc2 = fmaf(h2.w, w[4 * q + 11], acc2);
      acc3 = fmaf(h3.x, w[4 * q + 12], acc3);
      acc3 = fmaf(h3.y, w[4 * q + 13], acc3);
      acc3 = fmaf(h3.z, w[4 * q + 14], acc3);
      acc3 = fmaf(h3.w, w[4 * q + 15], acc3);
    }
    float accs = ((acc0 + acc1) + (acc2 + acc3)) + xv;
    float a = is_g ? tanh_fast(accs) : sigm(accs);
    act[j] = a;
    LDS_BARRIER();  // act visible + all h_sh reads done
    if (j < HH) {
      float ig = act[j], fg = act[HH + j], gg = act[2 * HH + j], og = act[3 * HH + j];
      c = fmaf(fg, c, ig * gg);
      h_sh[j] = og * tanh_fast(c);
    }
    LDS_BARRIER();  // h_sh ready for next step
    xv = xn;
  }
  // classifier: out[b, cls] = h_T . W_fc[:, cls] + b_fc[cls]
  if (j < 4) {
    float acc = b_fc[j];
#pragma unroll 8
    for (int k = 0; k < HH; ++k) acc = fmaf(h_sh[k], W_fc[k * 4 + j], acc);
    out[b * 4 + j] = acc;
  }
}

extern "C" void kernel_launch(void* const* d_in, const int* in_sizes, int n_in,
                              void* d_out, int out_size, void* d_ws, size_t ws_size,
                              hipStream_t stream) {
  const float* x_seq   = (const float*)d_in[0];
  const int*   ei      = (const int*)d_in[1];
  const float* w_gat   = (const float*)d_in[2];
  const float* att_src = (const float*)d_in[3];
  const float* att_dst = (const float*)d_in[4];
  const float* b_gat   = (const float*)d_in[5];
  const float* W_ih    = (const float*)d_in[6];
  const float* W_hh    = (const float*)d_in[7];
  const float* b_ih    = (const float*)d_in[8];
  const float* b_hh    = (const float*)d_in[9];
  const float* W_fc    = (const float*)d_in[10];
  const float* b_fc    = (const float*)d_in[11];

  float* ws = (float*)d_ws;
  float* xw       = ws;                          // 16384*512 = 8388608 f
  float* W_eff    = xw + (size_t)NPOS * G4;      // 32*512    = 16384 f
  float* bias_eff = W_eff + NN * G4;             // 512 f
  float* scal     = bias_eff + G4;               // 2 f
  float* biasp    = scal + 2;                    // 32*512 f  (total ~33.7 MB)

  prep_kernel<<<NN, G4, 0, stream>>>(w_gat, b_gat, W_ih, W_eff, biasp);
  prep2_kernel<<<1, G4, 0, stream>>>(biasp, b_ih, b_hh, w_gat, att_src, att_dst, bias_eff, scal);
  gatxw_kernel<<<NPOS / 8, 256, 0, stream>>>(x_seq, ei, scal, W_eff, bias_eff, xw);
  lstm_kernel<<<BB, G4, 0, stream>>>(xw, W_hh, W_fc, b_fc, (float*)d_out);
}